// Round 15
// baseline (80.927 us; speedup 1.0000x reference)
//
#include <hip/hip_runtime.h>
#include <hip/hip_bf16.h>

#define N_NODES 2048
#define EMBED 256
#define STATE 128
#define HID 256
#define N_ACT 256
#define TEAMS 8
#define PAIR_F 14
#define BT_TOTAL 512               // B*T
#define M_TOTAL (BT_TOTAL * N_ACT) // 131072

typedef _Float16 f16_t;
typedef _Float16 f16x8 __attribute__((ext_vector_type(8)));
typedef _Float16 f16x4 __attribute__((ext_vector_type(4)));
typedef _Float16 f16x2 __attribute__((ext_vector_type(2)));
typedef float f32x4 __attribute__((ext_vector_type(4)));

// paR fragment layout: addr_halves(a, n) = (a>>4)*4096 + (n>>2)*64 + (a&15)*4 + (n&3)
__device__ __forceinline__ size_t par_idx(int a, int n) {
    return (size_t)(a >> 4) * 4096 + (size_t)(n >> 2) * 64 + (a & 15) * 4 + (n & 3);
}

// 8 consecutive rows of W at column n -> f16x8 (same RTN casts as old reorder path)
__device__ __forceinline__ f16x8 gather8(const float* __restrict__ W, int k0, int n, int ld) {
    f16x8 r;
#pragma unroll
    for (int j = 0; j < 8; ++j) r[j] = (f16_t)W[(size_t)(k0 + j) * ld + n];
    return r;
}

// 8 contiguous fp32 -> f16x8 (32B-aligned sources only)
__device__ __forceinline__ f16x8 load8_f32(const float* __restrict__ p) {
    float4 v0 = *(const float4*)p, v1 = *(const float4*)(p + 4);
    f16x8 r;
    r[0] = (f16_t)v0.x; r[1] = (f16_t)v0.y; r[2] = (f16_t)v0.z; r[3] = (f16_t)v0.w;
    r[4] = (f16_t)v1.x; r[5] = (f16_t)v1.y; r[6] = (f16_t)v1.z; r[7] = (f16_t)v1.w;
    return r;
}

__device__ __forceinline__ f16x2 pk_relu(f16x2 x) {
    f16x2 r;
    asm("v_pk_max_f16 %0, %1, %2" : "=v"(r) : "v"(x), "v"(f16x2{(_Float16)0, (_Float16)0}));
    return r;
}

__device__ __forceinline__ f16x2 cvt_pk(float lo, float hi) {
    return __builtin_bit_cast(f16x2, __builtin_amdgcn_cvt_pkrtz(lo, hi));
}

// ---------------- K1: ALL precompute in one launch ----------------
// blocks 0..15  : pbt rows bt0..+31 (se = relu(states@Ws+bs) in LDS, pbt = se@W1d)
//                 — Ws/W1d/states fragments inline-converted from fp32
// blocks 16..47 : pa tile 32x64 ([proc|team|gmean]@W1[0:768] + b1 -> paR)
//                 — gmean computed in-block from ne; ne/team/W1 inline-converted
// blocks 48..   : flat units: pf16 (262144), W2s (8192), w1pt (1024)
__global__ __launch_bounds__(256, 4) void k_all(
    const float* __restrict__ ne, const int* __restrict__ idx,
    const float* __restrict__ team, const float* __restrict__ states,
    const float* __restrict__ Ws, const float* __restrict__ W1,
    const float* __restrict__ W2, const float* __restrict__ pf,
    const float* __restrict__ bs, const float* __restrict__ b1,
    f16_t* __restrict__ W2s, f16_t* __restrict__ w1pt,
    f16_t* __restrict__ paR, f16_t* __restrict__ pbt_h,
    f16_t* __restrict__ pf16) {
    __shared__ __align__(16) f16_t se[32 * 256]; // pbt path
    __shared__ __align__(16) f16_t gml[256];     // pa path
    const int tid = threadIdx.x;
    const int wid = tid >> 6, lane = tid & 63;
    const int c = lane & 15, q = lane >> 4;
    int bid = blockIdx.x;

    if (bid < 48) {
        if (bid >= 16) { // ---- pa path: 32x64 tile ----
            // gmean: column tid over all 2048 nodes (redundant per block, L3-hot)
            {
                float s0 = 0, s1 = 0, s2 = 0, s3 = 0, s4 = 0, s5 = 0, s6 = 0, s7 = 0;
                const float* col = ne + tid;
                for (int r = 0; r < N_NODES; r += 8) {
                    s0 += col[(size_t)(r + 0) * EMBED]; s1 += col[(size_t)(r + 1) * EMBED];
                    s2 += col[(size_t)(r + 2) * EMBED]; s3 += col[(size_t)(r + 3) * EMBED];
                    s4 += col[(size_t)(r + 4) * EMBED]; s5 += col[(size_t)(r + 5) * EMBED];
                    s6 += col[(size_t)(r + 6) * EMBED]; s7 += col[(size_t)(r + 7) * EMBED];
                }
                float s = ((s0 + s1) + (s2 + s3)) + ((s4 + s5) + (s6 + s7));
                gml[tid] = (f16_t)(s * (1.0f / N_NODES));
            }
            __syncthreads();
            int b = bid - 16;
            const int m0 = (b >> 2) * 32, n0 = (b & 3) * 64;
            const int n = n0 + wid * 16 + c;
            f32x4 acc[2] = {f32x4{0, 0, 0, 0}, f32x4{0, 0, 0, 0}};
            const float* neb[2];
            const float* tmb[2];
#pragma unroll
            for (int mi = 0; mi < 2; ++mi) {
                int m = m0 + mi * 16 + c;
                neb[mi] = ne + (size_t)idx[m] * EMBED;
                tmb[mi] = team + (size_t)(m % TEAMS) * EMBED;
            }
            // ks 0..7: proc (ne rows); ks 8..15: team
#pragma unroll
            for (int ks = 0; ks < 16; ++ks) {
                f16x8 bf = gather8(W1, ks * 32 + q * 8, n, HID);
#pragma unroll
                for (int mi = 0; mi < 2; ++mi) {
                    int e0 = ks * 32 + q * 8;
                    const float* src = (ks < 8) ? (neb[mi] + e0) : (tmb[mi] + (e0 - 256));
                    f16x8 af = load8_f32(src);
                    acc[mi] = __builtin_amdgcn_mfma_f32_16x16x32_f16(af, bf, acc[mi], 0, 0, 0);
                }
            }
            // ks 16..23: gmean (A uniform, from LDS broadcast)
#pragma unroll
            for (int ks = 0; ks < 8; ++ks) {
                f16x8 bf = gather8(W1, 512 + ks * 32 + q * 8, n, HID);
                f16x8 af = *(const f16x8*)(gml + ks * 32 + q * 8);
#pragma unroll
                for (int mi = 0; mi < 2; ++mi)
                    acc[mi] = __builtin_amdgcn_mfma_f32_16x16x32_f16(af, bf, acc[mi], 0, 0, 0);
            }
            float b1v = b1[n];
#pragma unroll
            for (int mi = 0; mi < 2; ++mi)
#pragma unroll
                for (int j = 0; j < 4; ++j) {
                    int a = m0 + mi * 16 + q * 4 + j;
                    paR[par_idx(a, n)] = (f16_t)(acc[mi][j] + b1v);
                }
            return;
        }

        // ---- pbt path: 32 rows of bt ----
        const int bt0 = bid * 32;
        f32x4 acc[2][4];
#pragma unroll
        for (int mi = 0; mi < 2; ++mi)
#pragma unroll
            for (int ni = 0; ni < 4; ++ni) acc[mi][ni] = f32x4{0, 0, 0, 0};
        // phase A: se = relu(states@Ws + bs)
#pragma unroll
        for (int ks = 0; ks < 4; ++ks) {
            f16x8 bh[4];
#pragma unroll
            for (int ni = 0; ni < 4; ++ni)
                bh[ni] = gather8(Ws, ks * 32 + q * 8, (wid * 4 + ni) * 16 + c, EMBED);
#pragma unroll
            for (int mi = 0; mi < 2; ++mi) {
                f16x8 af = load8_f32(states + (size_t)(bt0 + mi * 16 + c) * STATE + ks * 32 + q * 8);
#pragma unroll
                for (int ni = 0; ni < 4; ++ni)
                    acc[mi][ni] = __builtin_amdgcn_mfma_f32_16x16x32_f16(af, bh[ni], acc[mi][ni], 0, 0, 0);
            }
        }
#pragma unroll
        for (int mi = 0; mi < 2; ++mi)
#pragma unroll
            for (int ni = 0; ni < 4; ++ni) {
                float bsv = bs[wid * 64 + ni * 16 + c];
#pragma unroll
                for (int j = 0; j < 4; ++j) {
                    int m = mi * 16 + q * 4 + j;
                    int n = wid * 64 + ni * 16 + c;
                    se[m * 256 + (n ^ ((m & 7) << 3))] = (f16_t)fmaxf(acc[mi][ni][j] + bsv, 0.f);
                }
            }
#pragma unroll
        for (int mi = 0; mi < 2; ++mi)
#pragma unroll
            for (int ni = 0; ni < 4; ++ni) acc[mi][ni] = f32x4{0, 0, 0, 0};
        __syncthreads();
        // phase B: pbt = se @ W1d (K=256), W1d inline from W1 rows 768..1023
#pragma unroll
        for (int ks = 0; ks < 8; ++ks) {
            f16x8 bh[4];
#pragma unroll
            for (int ni = 0; ni < 4; ++ni)
                bh[ni] = gather8(W1, 768 + ks * 32 + q * 8, (wid * 4 + ni) * 16 + c, HID);
#pragma unroll
            for (int mi = 0; mi < 2; ++mi) {
                int m = mi * 16 + c;
                f16x8 ah = *(const f16x8*)(&se[m * 256 + ((ks * 32 + q * 8) ^ ((m & 7) << 3))]);
#pragma unroll
                for (int ni = 0; ni < 4; ++ni)
                    acc[mi][ni] = __builtin_amdgcn_mfma_f32_16x16x32_f16(ah, bh[ni], acc[mi][ni], 0, 0, 0);
            }
        }
#pragma unroll
        for (int mi = 0; mi < 2; ++mi)
#pragma unroll
            for (int ni = 0; ni < 4; ++ni)
#pragma unroll
                for (int j = 0; j < 4; ++j)
                    pbt_h[(size_t)(bt0 + mi * 16 + q * 4 + j) * HID + wid * 64 + ni * 16 + c] =
                        (f16_t)acc[mi][ni][j];
        return;
    }

    // ---- flat-unit segments ----
    int u = (bid - 48) * 256 + tid;
    if (u < 262144) { // pf16 [M][16]: unit u -> row m = u>>1, half h = u&1
        int m = u >> 1, h = u & 1;
        const float* row = pf + (size_t)m * PAIR_F;
        f16x8 r;
        if (h == 0) {
#pragma unroll
            for (int j = 0; j < 4; ++j) {
                float2 v = *(const float2*)(row + j * 2);
                r[j * 2] = (f16_t)v.x; r[j * 2 + 1] = (f16_t)v.y;
            }
        } else {
#pragma unroll
            for (int j = 0; j < 3; ++j) {
                float2 v = *(const float2*)(row + 8 + j * 2);
                r[j * 2] = (f16_t)v.x; r[j * 2 + 1] = (f16_t)v.y;
            }
            r[6] = (f16_t)0.f; r[7] = (f16_t)0.f;
        }
        *(f16x8*)(pf16 + (size_t)u * 8) = r;
        return;
    }
    u -= 262144;
    if (u < 8192) { // W2s KB=8
        int c2 = u & 15, q2 = (u >> 4) & 3, kb = (u >> 6) & 7, g = u >> 9;
        *(f16x8*)(W2s + (size_t)u * 8) = gather8(W2, kb * 32 + q2 * 8, g * 16 + c2, HID);
        return;
    }
    u -= 8192;
    if (u < 1024) { // w1pt KB=1, base 1024, pad 14->32
        int c2 = u & 15, q2 = (u >> 4) & 3, g = u >> 6;
        int n = g * 16 + c2, k0 = q2 * 8;
        f16x8 r;
#pragma unroll
        for (int j = 0; j < 8; ++j) {
            int k = k0 + j;
            r[j] = (f16_t)((k < PAIR_F) ? W1[(size_t)(1024 + k) * HID + n] : 0.f);
        }
        *(f16x8*)(w1pt + (size_t)u * 8) = r;
    }
}

// ---------------- K2: fused main kernel (round-13 structure, unchanged) ----------------
// BM=128: 512 thr / 8 fat waves; wave = 64 rows x 64 cols (wr=wid>>2, wc=wid&3).
__global__ __launch_bounds__(512, 4) void k_main(
    const f16_t* __restrict__ pf16, const f16_t* __restrict__ paR,
    const f16_t* __restrict__ pbt, const f16_t* __restrict__ w2s,
    const f16_t* __restrict__ w1pt, const float* __restrict__ b2,
    const float* __restrict__ W3, const float* __restrict__ b3,
    float* __restrict__ out) {
    __shared__ __align__(16) f16_t Ah[128 * 256];
    __shared__ float red[4][128];

    const int tid = threadIdx.x;
    const int wid = tid >> 6, lane = tid & 63;
    const int wr = wid >> 2, wc = wid & 3;
    const int c = lane & 15, q = lane >> 4;

    const int r0 = blockIdx.x * 128;
    const int bt = r0 >> 8;
    const int a0 = r0 & 255;

    f32x4 acc[16];
#pragma unroll
    for (int i = 0; i < 16; ++i) acc[i] = f32x4{0, 0, 0, 0};

    f16x4 pbtv[4];
#pragma unroll
    for (int nf = 0; nf < 4; ++nf)
        pbtv[nf] = *(const f16x4*)(pbt + (size_t)bt * HID + wc * 64 + nf * 16 + q * 4);

    f16x8 af[4];
#pragma unroll
    for (int nf = 0; nf < 4; ++nf) {
        int g = wc * 4 + nf;
        af[nf] = *(const f16x8*)(w1pt + (size_t)(g * 4 + q) * 128 + c * 8);
    }

    f16x4 pavA[4], pavB[4];
    {
        int n0 = wc * 64 + 0 * 16 + q * 4;
#pragma unroll
        for (int mf = 0; mf < 4; ++mf)
            pavA[mf] = *(const f16x4*)(paR + (size_t)((a0 >> 4) + wr * 4 + mf) * 4096 +
                                       (size_t)(n0 >> 2) * 64 + c * 4);
    }

    // ---- phase 1: transposed pair GEMM: D[n][m] = w1pt (A) x pf16^T (B)
#pragma unroll
    for (int mf = 0; mf < 4; ++mf) {
        int m = wr * 64 + mf * 16 + c;
        f16x8 bf;
        if (q < 2) bf = *(const f16x8*)(pf16 + (size_t)(r0 + m) * 16 + q * 8);
        else bf = f16x8{(_Float16)0, (_Float16)0, (_Float16)0, (_Float16)0,
                        (_Float16)0, (_Float16)0, (_Float16)0, (_Float16)0};
        __builtin_amdgcn_s_setprio(1);
#pragma unroll
        for (int nf = 0; nf < 4; ++nf)
            acc[nf * 4 + mf] = __builtin_amdgcn_mfma_f32_16x16x32_f16(af[nf], bf, acc[nf * 4 + mf], 0, 0, 0);
        __builtin_amdgcn_s_setprio(0);
    }

    // ---- h1 = relu(pair + pa + pbt) -> f16 (packed), swizzled LDS; pav pipelined
#pragma unroll
    for (int nf = 0; nf < 4; ++nf) {
        if (nf < 3) {
            int n1 = wc * 64 + (nf + 1) * 16 + q * 4;
#pragma unroll
            for (int mf = 0; mf < 4; ++mf)
                pavB[mf] = *(const f16x4*)(paR + (size_t)((a0 >> 4) + wr * 4 + mf) * 4096 +
                                           (size_t)(n1 >> 2) * 64 + c * 4);
        }
        int n0 = wc * 64 + nf * 16 + q * 4;
        f16x2 pb01 = {pbtv[nf][0], pbtv[nf][1]}, pb23 = {pbtv[nf][2], pbtv[nf][3]};
#pragma unroll
        for (int mf = 0; mf < 4; ++mf) {
            int m = wr * 64 + mf * 16 + c;
            f16x2 pa01 = {pavA[mf][0], pavA[mf][1]}, pa23 = {pavA[mf][2], pavA[mf][3]};
            f32x4 a = acc[nf * 4 + mf];
            f16x2 h01 = cvt_pk(a[0], a[1]);
            f16x2 h23 = cvt_pk(a[2], a[3]);
            h01 = pk_relu(h01 + pa01 + pb01);
            h23 = pk_relu(h23 + pa23 + pb23);
            f16x4 hv = __builtin_shufflevector(h01, h23, 0, 1, 2, 3);
            *(f16x4*)(&Ah[m * 256 + (n0 ^ ((m & 7) << 3))]) = hv;
        }
#pragma unroll
        for (int mf = 0; mf < 4; ++mf) pavA[mf] = pavB[mf];
    }

#pragma unroll
    for (int i = 0; i < 16; ++i) acc[i] = f32x4{0, 0, 0, 0};

    // pre-barrier B prefetch for ks=0
    f16x8 bh[4];
#pragma unroll
    for (int ni = 0; ni < 4; ++ni) {
        int g = wc * 4 + ni;
        bh[ni] = *(const f16x8*)(w2s + (size_t)((g * 8 + 0) * 4 + q) * 128 + c * 8);
    }

    __syncthreads();

    // ---- phase 2: h2 = h1[128x256] @ W2[256x256]; ah 1-deep prefetch + setprio
#pragma unroll
    for (int ks = 0; ks < 8; ++ks) {
        f16x8 bhn[4];
        if (ks < 7) {
#pragma unroll
            for (int ni = 0; ni < 4; ++ni) {
                int g = wc * 4 + ni;
                bhn[ni] = *(const f16x8*)(w2s + (size_t)((g * 8 + ks + 1) * 4 + q) * 128 + c * 8);
            }
        }
        f16x8 ahA, ahB;
        {
            int m = wr * 64 + 0 * 16 + c;
            ahA = *(const f16x8*)(&Ah[m * 256 + ((ks * 32 + q * 8) ^ ((m & 7) << 3))]);
        }
        __builtin_amdgcn_s_setprio(1);
#pragma unroll
        for (int mi = 0; mi < 4; ++mi) {
            if (mi < 3) {
                int m1 = wr * 64 + (mi + 1) * 16 + c;
                ahB = *(const f16x8*)(&Ah[m1 * 256 + ((ks * 32 + q * 8) ^ ((m1 & 7) << 3))]);
            }
#pragma unroll
            for (int ni = 0; ni < 4; ++ni)
                acc[mi * 4 + ni] = __builtin_amdgcn_mfma_f32_16x16x32_f16(ahA, bh[ni], acc[mi * 4 + ni], 0, 0, 0);
            ahA = ahB;
        }
        __builtin_amdgcn_s_setprio(0);
#pragma unroll
        for (int ni = 0; ni < 4; ++ni) bh[ni] = bhn[ni];
    }

    // ---- epilogue: score[m] = sum_n relu(h2 + b2) * W3 (+ b3)
    float p[4][4];
#pragma unroll
    for (int mi = 0; mi < 4; ++mi)
#pragma unroll
        for (int j = 0; j < 4; ++j) p[mi][j] = 0.f;
#pragma unroll
    for (int ni = 0; ni < 4; ++ni) {
        int n = wc * 64 + ni * 16 + c;
        float b2v = b2[n];
        float w3v = W3[n];
#pragma unroll
        for (int mi = 0; mi < 4; ++mi)
#pragma unroll
            for (int j = 0; j < 4; ++j)
                p[mi][j] = fmaf(fmaxf(acc[mi * 4 + ni][j] + b2v, 0.f), w3v, p[mi][j]);
    }
#pragma unroll
    for (int off = 1; off < 16; off <<= 1)
#pragma unroll
        for (int mi = 0; mi < 4; ++mi)
#pragma unroll
            for (int j = 0; j < 4; ++j) p[mi][j] += __shfl_xor(p[mi][j], off, 64);

    if (c == 0) {
#pragma unroll
        for (int mi = 0; mi < 4; ++mi)
#pragma unroll
            for (int j = 0; j < 4; ++j) red[wc][wr * 64 + mi * 16 + q * 4 + j] = p[mi][j];
    }
    __syncthreads();

    if (tid < 128) {
        out[(size_t)r0 + tid] = red[0][tid] + red[1][tid] + red[2][tid] + red[3][tid] + b3[0];
    }
}

// ---------------- launch ----------------
extern "C" void kernel_launch(void* const* d_in, const int* in_sizes, int n_in,
                              void* d_out, int out_size, void* d_ws, size_t ws_size,
                              hipStream_t stream) {
    (void)in_sizes; (void)n_in; (void)out_size; (void)ws_size;
    const float* ne     = (const float*)d_in[0];
    const float* states = (const float*)d_in[1];
    const float* pf     = (const float*)d_in[2];
    const int*   idx    = (const int*)d_in[3];
    const float* team   = (const float*)d_in[4];
    const float* Ws     = (const float*)d_in[5];
    const float* bs     = (const float*)d_in[6];
    const float* W1     = (const float*)d_in[7];
    const float* b1     = (const float*)d_in[8];
    const float* W2     = (const float*)d_in[9];
    const float* b2     = (const float*)d_in[10];
    const float* W3     = (const float*)d_in[11];
    const float* b3     = (const float*)d_in[12];
    float* out = (float*)d_out;

    char* ws = (char*)d_ws;
    f16_t* W2s   = (f16_t*)(ws + 0);        // 131072
    f16_t* w1pt  = (f16_t*)(ws + 131072);   //  16384
    f16_t* paR   = (f16_t*)(ws + 147456);   // 131072
    f16_t* pbt_h = (f16_t*)(ws + 278528);   // 262144
    f16_t* pf16  = (f16_t*)(ws + 540672);   // 4194304 (end 4734976)

    // 48 pp-blocks + (262144 + 8192 + 1024)/256 = 1060 unit-blocks
    k_all<<<48 + 1060, 256, 0, stream>>>(ne, idx, team, states, Ws, W1, W2, pf,
                                         bs, b1, W2s, w1pt, paR, pbt_h, pf16);
    k_main<<<M_TOTAL / 128, 512, 0, stream>>>(pf16, paR, pbt_h, W2s, w1pt, b2, W3, b3, out);
}

// Round 16
// 42.779 us; speedup vs baseline: 1.8918x; 1.8918x over previous
//
#include <hip/hip_runtime.h>
#include <hip/hip_bf16.h>

#define N_NODES 2048
#define EMBED 256
#define STATE 128
#define HID 256
#define N_ACT 256
#define TEAMS 8
#define PAIR_F 14
#define BT_TOTAL 512               // B*T
#define M_TOTAL (BT_TOTAL * N_ACT) // 131072

typedef _Float16 f16_t;
typedef _Float16 f16x8 __attribute__((ext_vector_type(8)));
typedef _Float16 f16x4 __attribute__((ext_vector_type(4)));
typedef _Float16 f16x2 __attribute__((ext_vector_type(2)));
typedef float f32x4 __attribute__((ext_vector_type(4)));

// paR fragment layout: addr_halves(a, n) = (a>>4)*4096 + (n>>2)*64 + (a&15)*4 + (n&3)
__device__ __forceinline__ size_t par_idx(int a, int n) {
    return (size_t)(a >> 4) * 4096 + (size_t)(n >> 2) * 64 + (a & 15) * 4 + (n & 3);
}

__device__ __forceinline__ f16x8 gather8(const float* __restrict__ W, int k0, int n, int ld) {
    f16x8 r;
#pragma unroll
    for (int j = 0; j < 8; ++j) r[j] = (f16_t)W[(size_t)(k0 + j) * ld + n];
    return r;
}

__device__ __forceinline__ f16x2 pk_relu(f16x2 x) {
    f16x2 r;
    asm("v_pk_max_f16 %0, %1, %2" : "=v"(r) : "v"(x), "v"(f16x2{(_Float16)0, (_Float16)0}));
    return r;
}

__device__ __forceinline__ f16x2 cvt_pk(float lo, float hi) {
    return __builtin_bit_cast(f16x2, __builtin_amdgcn_cvt_pkrtz(lo, hi));
}

// ---------------- K1: prep-A — ONLY what k_pp consumes ----------------
// blocks 0..63: gpart column partial sums; then flat f16x8 units:
// vecs(16384) W1abT(16384) W1cT(8192) W1dT(8192) WsT(4096) states_h(8192)
__global__ void k_prepA(const float* __restrict__ ne, const int* __restrict__ idx,
                        const float* __restrict__ team, const float* __restrict__ states,
                        const float* __restrict__ Ws, const float* __restrict__ W1,
                        float* __restrict__ gpart, f16_t* __restrict__ vecs,
                        f16_t* __restrict__ W1abT, f16_t* __restrict__ W1cT,
                        f16_t* __restrict__ W1dT, f16_t* __restrict__ WsT,
                        f16_t* __restrict__ states_h) {
    int bid = blockIdx.x;
    if (bid < 64) {
        int t = threadIdx.x;
        float s = 0.f;
        const float* base = ne + (size_t)bid * 32 * EMBED + t;
#pragma unroll
        for (int i = 0; i < 32; ++i) s += base[(size_t)i * EMBED];
        gpart[bid * EMBED + t] = s;
        return;
    }
    int u = (bid - 64) * 256 + threadIdx.x;
    if (u < 16384) { // vecs [256][512]
        int a = u >> 6, e = (u & 63) * 8;
        f16x8 r;
        if (e < 256) {
            const float* src = ne + (size_t)idx[a] * EMBED + e;
#pragma unroll
            for (int j = 0; j < 8; ++j) r[j] = (f16_t)src[j];
        } else {
            const float* src = team + (size_t)(a % TEAMS) * EMBED + (e - 256);
#pragma unroll
            for (int j = 0; j < 8; ++j) r[j] = (f16_t)src[j];
        }
        *(f16x8*)(vecs + (size_t)u * 8) = r;
        return;
    }
    u -= 16384;
    if (u < 16384) { // W1abT KB=16
        int c = u & 15, q = (u >> 4) & 3, kb = (u >> 6) & 15, g = u >> 10;
        *(f16x8*)(W1abT + (size_t)u * 8) = gather8(W1, kb * 32 + q * 8, g * 16 + c, HID);
        return;
    }
    u -= 16384;
    if (u < 8192) { // W1cT KB=8, base 512
        int c = u & 15, q = (u >> 4) & 3, kb = (u >> 6) & 7, g = u >> 9;
        *(f16x8*)(W1cT + (size_t)u * 8) = gather8(W1, 512 + kb * 32 + q * 8, g * 16 + c, HID);
        return;
    }
    u -= 8192;
    if (u < 8192) { // W1dT KB=8, base 768
        int c = u & 15, q = (u >> 4) & 3, kb = (u >> 6) & 7, g = u >> 9;
        *(f16x8*)(W1dT + (size_t)u * 8) = gather8(W1, 768 + kb * 32 + q * 8, g * 16 + c, HID);
        return;
    }
    u -= 8192;
    if (u < 4096) { // WsT KB=4
        int c = u & 15, q = (u >> 4) & 3, kb = (u >> 6) & 3, g = u >> 8;
        *(f16x8*)(WsT + (size_t)u * 8) = gather8(Ws, kb * 32 + q * 8, g * 16 + c, EMBED);
        return;
    }
    u -= 4096;
    if (u < 8192) { // states_h copy
        const float* src = states + (size_t)u * 8;
        f16x8 r;
#pragma unroll
        for (int j = 0; j < 8; ++j) r[j] = (f16_t)src[j];
        *(f16x8*)(states_h + (size_t)u * 8) = r;
    }
}

// ---------------- K2: prep-B + pp — pp blocks hidden under 1060 unit blocks ----------------
// blocks 0..15 : pbt rows bt0..+31 (round-13 k_pp code, coalesced reordered inputs)
// blocks 16..47: pa tile 32x64 (round-13 k_pp code)
// blocks 48..  : flat units: pf16(262144) W2s(8192) w1pt(1024)
__global__ __launch_bounds__(256, 4) void k_prepB(
    const float* __restrict__ pf, const float* __restrict__ W1,
    const float* __restrict__ W2, const f16_t* __restrict__ states_h,
    const f16_t* __restrict__ WsT, const float* __restrict__ bs,
    const f16_t* __restrict__ W1dT, const f16_t* __restrict__ vecs,
    const f16_t* __restrict__ W1abT, const f16_t* __restrict__ W1cT,
    const float* __restrict__ gpart, const float* __restrict__ b1,
    f16_t* __restrict__ W2s, f16_t* __restrict__ w1pt,
    f16_t* __restrict__ paR, f16_t* __restrict__ pbt_h,
    f16_t* __restrict__ pf16) {
    __shared__ __align__(16) f16_t se[32 * 256];
    __shared__ __align__(16) f16_t gml[256];
    const int tid = threadIdx.x;
    const int wid = tid >> 6, lane = tid & 63;
    const int c = lane & 15, q = lane >> 4;
    int bid = blockIdx.x;

    if (bid < 48) {
        if (bid >= 16) { // ---- pa path: 32x64 tile ----
            {
                float s = 0.f;
#pragma unroll 8
                for (int p = 0; p < 64; ++p) s += gpart[p * EMBED + tid];
                gml[tid] = (f16_t)(s * (1.0f / N_NODES));
            }
            __syncthreads();
            int b = bid - 16;
            const int m0 = (b >> 2) * 32, n0 = (b & 3) * 64;
            const int n = n0 + wid * 16 + c;
            const int g = n >> 4;
            f32x4 acc[2] = {f32x4{0, 0, 0, 0}, f32x4{0, 0, 0, 0}};
            for (int ks = 0; ks < 16; ++ks) {
                f16x8 bf = *(const f16x8*)(W1abT + (size_t)((g * 16 + ks) * 4 + q) * 128 + c * 8);
#pragma unroll
                for (int mi = 0; mi < 2; ++mi) {
                    f16x8 af = *(const f16x8*)(vecs + (size_t)(m0 + mi * 16 + c) * 512 + ks * 32 + q * 8);
                    acc[mi] = __builtin_amdgcn_mfma_f32_16x16x32_f16(af, bf, acc[mi], 0, 0, 0);
                }
            }
#pragma unroll
            for (int ks = 0; ks < 8; ++ks) {
                f16x8 bf = *(const f16x8*)(W1cT + (size_t)((g * 8 + ks) * 4 + q) * 128 + c * 8);
                f16x8 af = *(const f16x8*)(gml + ks * 32 + q * 8);
#pragma unroll
                for (int mi = 0; mi < 2; ++mi)
                    acc[mi] = __builtin_amdgcn_mfma_f32_16x16x32_f16(af, bf, acc[mi], 0, 0, 0);
            }
            float b1v = b1[n];
#pragma unroll
            for (int mi = 0; mi < 2; ++mi)
#pragma unroll
                for (int j = 0; j < 4; ++j) {
                    int a = m0 + mi * 16 + q * 4 + j;
                    paR[par_idx(a, n)] = (f16_t)(acc[mi][j] + b1v);
                }
            return;
        }

        // ---- pbt path: 32 rows ----
        const int bt0 = bid * 32;
        f32x4 acc[2][4];
#pragma unroll
        for (int mi = 0; mi < 2; ++mi)
#pragma unroll
            for (int ni = 0; ni < 4; ++ni) acc[mi][ni] = f32x4{0, 0, 0, 0};
#pragma unroll
        for (int ks = 0; ks < 4; ++ks) {
            f16x8 bh[4];
#pragma unroll
            for (int ni = 0; ni < 4; ++ni) {
                int g = wid * 4 + ni;
                bh[ni] = *(const f16x8*)(WsT + (size_t)((g * 4 + ks) * 4 + q) * 128 + c * 8);
            }
#pragma unroll
            for (int mi = 0; mi < 2; ++mi) {
                f16x8 af = *(const f16x8*)(states_h + (size_t)(bt0 + mi * 16 + c) * STATE + ks * 32 + q * 8);
#pragma unroll
                for (int ni = 0; ni < 4; ++ni)
                    acc[mi][ni] = __builtin_amdgcn_mfma_f32_16x16x32_f16(af, bh[ni], acc[mi][ni], 0, 0, 0);
            }
        }
#pragma unroll
        for (int mi = 0; mi < 2; ++mi)
#pragma unroll
            for (int ni = 0; ni < 4; ++ni) {
                float bsv = bs[wid * 64 + ni * 16 + c];
#pragma unroll
                for (int j = 0; j < 4; ++j) {
                    int m = mi * 16 + q * 4 + j;
                    int n = wid * 64 + ni * 16 + c;
                    se[m * 256 + (n ^ ((m & 7) << 3))] = (f16_t)fmaxf(acc[mi][ni][j] + bsv, 0.f);
                }
            }
#pragma unroll
        for (int mi = 0; mi < 2; ++mi)
#pragma unroll
            for (int ni = 0; ni < 4; ++ni) acc[mi][ni] = f32x4{0, 0, 0, 0};
        __syncthreads();
#pragma unroll
        for (int ks = 0; ks < 8; ++ks) {
            f16x8 bh[4];
#pragma unroll
            for (int ni = 0; ni < 4; ++ni) {
                int g = wid * 4 + ni;
                bh[ni] = *(const f16x8*)(W1dT + (size_t)((g * 8 + ks) * 4 + q) * 128 + c * 8);
            }
#pragma unroll
            for (int mi = 0; mi < 2; ++mi) {
                int m = mi * 16 + c;
                f16x8 ah = *(const f16x8*)(&se[m * 256 + ((ks * 32 + q * 8) ^ ((m & 7) << 3))]);
#pragma unroll
                for (int ni = 0; ni < 4; ++ni)
                    acc[mi][ni] = __builtin_amdgcn_mfma_f32_16x16x32_f16(ah, bh[ni], acc[mi][ni], 0, 0, 0);
            }
        }
#pragma unroll
        for (int mi = 0; mi < 2; ++mi)
#pragma unroll
            for (int ni = 0; ni < 4; ++ni)
#pragma unroll
                for (int j = 0; j < 4; ++j)
                    pbt_h[(size_t)(bt0 + mi * 16 + q * 4 + j) * HID + wid * 64 + ni * 16 + c] =
                        (f16_t)acc[mi][ni][j];
        return;
    }

    // ---- flat-unit segments ----
    int u = (bid - 48) * 256 + tid;
    if (u < 262144) { // pf16 [M][16]
        int m = u >> 1, h = u & 1;
        const float* row = pf + (size_t)m * PAIR_F;
        f16x8 r;
        if (h == 0) {
#pragma unroll
            for (int j = 0; j < 4; ++j) {
                float2 v = *(const float2*)(row + j * 2);
                r[j * 2] = (f16_t)v.x; r[j * 2 + 1] = (f16_t)v.y;
            }
        } else {
#pragma unroll
            for (int j = 0; j < 3; ++j) {
                float2 v = *(const float2*)(row + 8 + j * 2);
                r[j * 2] = (f16_t)v.x; r[j * 2 + 1] = (f16_t)v.y;
            }
            r[6] = (f16_t)0.f; r[7] = (f16_t)0.f;
        }
        *(f16x8*)(pf16 + (size_t)u * 8) = r;
        return;
    }
    u -= 262144;
    if (u < 8192) { // W2s KB=8
        int c2 = u & 15, q2 = (u >> 4) & 3, kb = (u >> 6) & 7, g = u >> 9;
        *(f16x8*)(W2s + (size_t)u * 8) = gather8(W2, kb * 32 + q2 * 8, g * 16 + c2, HID);
        return;
    }
    u -= 8192;
    if (u < 1024) { // w1pt KB=1, base 1024, pad 14->32
        int c2 = u & 15, q2 = (u >> 4) & 3, g = u >> 6;
        int n = g * 16 + c2, k0 = q2 * 8;
        f16x8 r;
#pragma unroll
        for (int j = 0; j < 8; ++j) {
            int k = k0 + j;
            r[j] = (f16_t)((k < PAIR_F) ? W1[(size_t)(1024 + k) * HID + n] : 0.f);
        }
        *(f16x8*)(w1pt + (size_t)u * 8) = r;
    }
}

// ---------------- K3: fused main kernel (round-13 structure, unchanged) ----------------
// BM=128: 512 thr / 8 fat waves; wave = 64 rows x 64 cols (wr=wid>>2, wc=wid&3).
__global__ __launch_bounds__(512, 4) void k_main(
    const f16_t* __restrict__ pf16, const f16_t* __restrict__ paR,
    const f16_t* __restrict__ pbt, const f16_t* __restrict__ w2s,
    const f16_t* __restrict__ w1pt, const float* __restrict__ b2,
    const float* __restrict__ W3, const float* __restrict__ b3,
    float* __restrict__ out) {
    __shared__ __align__(16) f16_t Ah[128 * 256];
    __shared__ float red[4][128];

    const int tid = threadIdx.x;
    const int wid = tid >> 6, lane = tid & 63;
    const int wr = wid >> 2, wc = wid & 3;
    const int c = lane & 15, q = lane >> 4;

    const int r0 = blockIdx.x * 128;
    const int bt = r0 >> 8;
    const int a0 = r0 & 255;

    f32x4 acc[16];
#pragma unroll
    for (int i = 0; i < 16; ++i) acc[i] = f32x4{0, 0, 0, 0};

    f16x4 pbtv[4];
#pragma unroll
    for (int nf = 0; nf < 4; ++nf)
        pbtv[nf] = *(const f16x4*)(pbt + (size_t)bt * HID + wc * 64 + nf * 16 + q * 4);

    f16x8 af[4];
#pragma unroll
    for (int nf = 0; nf < 4; ++nf) {
        int g = wc * 4 + nf;
        af[nf] = *(const f16x8*)(w1pt + (size_t)(g * 4 + q) * 128 + c * 8);
    }

    f16x4 pavA[4], pavB[4];
    {
        int n0 = wc * 64 + 0 * 16 + q * 4;
#pragma unroll
        for (int mf = 0; mf < 4; ++mf)
            pavA[mf] = *(const f16x4*)(paR + (size_t)((a0 >> 4) + wr * 4 + mf) * 4096 +
                                       (size_t)(n0 >> 2) * 64 + c * 4);
    }

    // ---- phase 1: transposed pair GEMM: D[n][m] = w1pt (A) x pf16^T (B)
#pragma unroll
    for (int mf = 0; mf < 4; ++mf) {
        int m = wr * 64 + mf * 16 + c;
        f16x8 bf;
        if (q < 2) bf = *(const f16x8*)(pf16 + (size_t)(r0 + m) * 16 + q * 8);
        else bf = f16x8{(_Float16)0, (_Float16)0, (_Float16)0, (_Float16)0,
                        (_Float16)0, (_Float16)0, (_Float16)0, (_Float16)0};
        __builtin_amdgcn_s_setprio(1);
#pragma unroll
        for (int nf = 0; nf < 4; ++nf)
            acc[nf * 4 + mf] = __builtin_amdgcn_mfma_f32_16x16x32_f16(af[nf], bf, acc[nf * 4 + mf], 0, 0, 0);
        __builtin_amdgcn_s_setprio(0);
    }

    // ---- h1 = relu(pair + pa + pbt) -> f16 (packed), swizzled LDS; pav pipelined
#pragma unroll
    for (int nf = 0; nf < 4; ++nf) {
        if (nf < 3) {
            int n1 = wc * 64 + (nf + 1) * 16 + q * 4;
#pragma unroll
            for (int mf = 0; mf < 4; ++mf)
                pavB[mf] = *(const f16x4*)(paR + (size_t)((a0 >> 4) + wr * 4 + mf) * 4096 +
                                           (size_t)(n1 >> 2) * 64 + c * 4);
        }
        int n0 = wc * 64 + nf * 16 + q * 4;
        f16x2 pb01 = {pbtv[nf][0], pbtv[nf][1]}, pb23 = {pbtv[nf][2], pbtv[nf][3]};
#pragma unroll
        for (int mf = 0; mf < 4; ++mf) {
            int m = wr * 64 + mf * 16 + c;
            f16x2 pa01 = {pavA[mf][0], pavA[mf][1]}, pa23 = {pavA[mf][2], pavA[mf][3]};
            f32x4 a = acc[nf * 4 + mf];
            f16x2 h01 = cvt_pk(a[0], a[1]);
            f16x2 h23 = cvt_pk(a[2], a[3]);
            h01 = pk_relu(h01 + pa01 + pb01);
            h23 = pk_relu(h23 + pa23 + pb23);
            f16x4 hv = __builtin_shufflevector(h01, h23, 0, 1, 2, 3);
            *(f16x4*)(&Ah[m * 256 + (n0 ^ ((m & 7) << 3))]) = hv;
        }
#pragma unroll
        for (int mf = 0; mf < 4; ++mf) pavA[mf] = pavB[mf];
    }

#pragma unroll
    for (int i = 0; i < 16; ++i) acc[i] = f32x4{0, 0, 0, 0};

    // pre-barrier B prefetch for ks=0
    f16x8 bh[4];
#pragma unroll
    for (int ni = 0; ni < 4; ++ni) {
        int g = wc * 4 + ni;
        bh[ni] = *(const f16x8*)(w2s + (size_t)((g * 8 + 0) * 4 + q) * 128 + c * 8);
    }

    __syncthreads();

    // ---- phase 2: h2 = h1[128x256] @ W2[256x256]; ah 1-deep prefetch + setprio
#pragma unroll
    for (int ks = 0; ks < 8; ++ks) {
        f16x8 bhn[4];
        if (ks < 7) {
#pragma unroll
            for (int ni = 0; ni < 4; ++ni) {
                int g = wc * 4 + ni;
                bhn[ni] = *(const f16x8*)(w2s + (size_t)((g * 8 + ks + 1) * 4 + q) * 128 + c * 8);
            }
        }
        f16x8 ahA, ahB;
        {
            int m = wr * 64 + 0 * 16 + c;
            ahA = *(const f16x8*)(&Ah[m * 256 + ((ks * 32 + q * 8) ^ ((m & 7) << 3))]);
        }
        __builtin_amdgcn_s_setprio(1);
#pragma unroll
        for (int mi = 0; mi < 4; ++mi) {
            if (mi < 3) {
                int m1 = wr * 64 + (mi + 1) * 16 + c;
                ahB = *(const f16x8*)(&Ah[m1 * 256 + ((ks * 32 + q * 8) ^ ((m1 & 7) << 3))]);
            }
#pragma unroll
            for (int ni = 0; ni < 4; ++ni)
                acc[mi * 4 + ni] = __builtin_amdgcn_mfma_f32_16x16x32_f16(ahA, bh[ni], acc[mi * 4 + ni], 0, 0, 0);
            ahA = ahB;
        }
        __builtin_amdgcn_s_setprio(0);
#pragma unroll
        for (int ni = 0; ni < 4; ++ni) bh[ni] = bhn[ni];
    }

    // ---- epilogue: score[m] = sum_n relu(h2 + b2) * W3 (+ b3)
    float p[4][4];
#pragma unroll
    for (int mi = 0; mi < 4; ++mi)
#pragma unroll
        for (int j = 0; j < 4; ++j) p[mi][j] = 0.f;
#pragma unroll
    for (int ni = 0; ni < 4; ++ni) {
        int n = wc * 64 + ni * 16 + c;
        float b2v = b2[n];
        float w3v = W3[n];
#pragma unroll
        for (int mi = 0; mi < 4; ++mi)
#pragma unroll
            for (int j = 0; j < 4; ++j)
                p[mi][j] = fmaf(fmaxf(acc[mi * 4 + ni][j] + b2v, 0.f), w3v, p[mi][j]);
    }
#pragma unroll
    for (int off = 1; off < 16; off <<= 1)
#pragma unroll
        for (int mi = 0; mi < 4; ++mi)
#pragma unroll
            for (int j = 0; j < 4; ++j) p[mi][j] += __shfl_xor(p[mi][j], off, 64);

    if (c == 0) {
#pragma unroll
        for (int mi = 0; mi < 4; ++mi)
#pragma unroll
            for (int j = 0; j < 4; ++j) red[wc][wr * 64 + mi * 16 + q * 4 + j] = p[mi][j];
    }
    __syncthreads();

    if (tid < 128) {
        out[(size_t)r0 + tid] = red[0][tid] + red[1][tid] + red[2][tid] + red[3][tid] + b3[0];
    }
}

// ---------------- launch ----------------
extern "C" void kernel_launch(void* const* d_in, const int* in_sizes, int n_in,
                              void* d_out, int out_size, void* d_ws, size_t ws_size,
                              hipStream_t stream) {
    (void)in_sizes; (void)n_in; (void)out_size; (void)ws_size;
    const float* ne     = (const float*)d_in[0];
    const float* states = (const float*)d_in[1];
    const float* pf     = (const float*)d_in[2];
    const int*   idx    = (const int*)d_in[3];
    const float* team   = (const float*)d_in[4];
    const float* Ws     = (const float*)d_in[5];
    const float* bs     = (const float*)d_in[6];
    const float* W1     = (const float*)d_in[7];
    const float* b1     = (const float*)d_in[8];
    const float* W2     = (const float*)d_in[9];
    const float* b2     = (const float*)d_in[10];
    const float* W3     = (const float*)d_in[11];
    const float* b3     = (const float*)d_in[12];
    float* out = (float*)d_out;

    char* ws = (char*)d_ws;
    float* gpart    = (float*)(ws + 0);        //  65536
    f16_t* vecs     = (f16_t*)(ws + 65536);    // 262144  [256][512]
    f16_t* W1abT    = (f16_t*)(ws + 327680);   // 262144
    f16_t* W1cT     = (f16_t*)(ws + 589824);   // 131072
    f16_t* W1dT     = (f16_t*)(ws + 720896);   // 131072
    f16_t* WsT      = (f16_t*)(ws + 851968);   //  65536
    f16_t* W2s      = (f16_t*)(ws + 917504);   // 131072
    f16_t* w1pt     = (f16_t*)(ws + 1048576);  //  16384
    f16_t* states_h = (f16_t*)(ws + 1064960);  // 131072
    f16_t* paR      = (f16_t*)(ws + 1196032);  // 131072
    f16_t* pbt_h    = (f16_t*)(ws + 1327104);  // 262144
    f16_t* pf16     = (f16_t*)(ws + 1589248);  // 4194304 (end 5783552)

    // K1: 64 colsum + (16384+16384+8192+8192+4096+8192)/256 = 240 unit blocks
    k_prepA<<<64 + 240, 256, 0, stream>>>(ne, idx, team, states, Ws, W1,
                                          gpart, vecs, W1abT, W1cT, W1dT, WsT, states_h);
    // K2: 48 pp blocks + (262144+8192+1024)/256 = 1060 unit blocks
    k_prepB<<<48 + 1060, 256, 0, stream>>>(pf, W1, W2, states_h, WsT, bs, W1dT,
                                           vecs, W1abT, W1cT, gpart, b1,
                                           W2s, w1pt, paR, pbt_h, pf16);
    k_main<<<M_TOTAL / 128, 512, 0, stream>>>(pf16, paR, pbt_h, W2s, w1pt, b2, W3, b3, out);
}

// Round 17
// 42.658 us; speedup vs baseline: 1.8971x; 1.0028x over previous
//
#include <hip/hip_runtime.h>
#include <hip/hip_bf16.h>

#define N_NODES 2048
#define EMBED 256
#define STATE 128
#define HID 256
#define N_ACT 256
#define TEAMS 8
#define PAIR_F 14
#define BT_TOTAL 512               // B*T
#define M_TOTAL (BT_TOTAL * N_ACT) // 131072

typedef _Float16 f16_t;
typedef _Float16 f16x8 __attribute__((ext_vector_type(8)));
typedef _Float16 f16x4 __attribute__((ext_vector_type(4)));
typedef _Float16 f16x2 __attribute__((ext_vector_type(2)));
typedef float f32x4 __attribute__((ext_vector_type(4)));

// paR fragment layout: addr_halves(a, n) = (a>>4)*4096 + (n>>2)*64 + (a&15)*4 + (n&3)
__device__ __forceinline__ size_t par_idx(int a, int n) {
    return (size_t)(a >> 4) * 4096 + (size_t)(n >> 2) * 64 + (a & 15) * 4 + (n & 3);
}

__device__ __forceinline__ f16x8 gather8(const float* __restrict__ W, int k0, int n, int ld) {
    f16x8 r;
#pragma unroll
    for (int j = 0; j < 8; ++j) r[j] = (f16_t)W[(size_t)(k0 + j) * ld + n];
    return r;
}

__device__ __forceinline__ f16x2 pk_relu(f16x2 x) {
    f16x2 r;
    asm("v_pk_max_f16 %0, %1, %2" : "=v"(r) : "v"(x), "v"(f16x2{(_Float16)0, (_Float16)0}));
    return r;
}

__device__ __forceinline__ f16x2 cvt_pk(float lo, float hi) {
    return __builtin_bit_cast(f16x2, __builtin_amdgcn_cvt_pkrtz(lo, hi));
}

// ---------------- K1: prep-A — ONLY what k_pp consumes ----------------
// blocks 0..63: gpart column partial sums; then flat f16x8 units:
// vecs(16384) W1abT(16384) W1cT(8192) W1dT(8192) WsT(4096) states_h(8192)
__global__ void k_prepA(const float* __restrict__ ne, const int* __restrict__ idx,
                        const float* __restrict__ team, const float* __restrict__ states,
                        const float* __restrict__ Ws, const float* __restrict__ W1,
                        float* __restrict__ gpart, f16_t* __restrict__ vecs,
                        f16_t* __restrict__ W1abT, f16_t* __restrict__ W1cT,
                        f16_t* __restrict__ W1dT, f16_t* __restrict__ WsT,
                        f16_t* __restrict__ states_h) {
    int bid = blockIdx.x;
    if (bid < 64) {
        int t = threadIdx.x;
        float s = 0.f;
        const float* base = ne + (size_t)bid * 32 * EMBED + t;
#pragma unroll
        for (int i = 0; i < 32; ++i) s += base[(size_t)i * EMBED];
        gpart[bid * EMBED + t] = s;
        return;
    }
    int u = (bid - 64) * 256 + threadIdx.x;
    if (u < 16384) { // vecs [256][512]
        int a = u >> 6, e = (u & 63) * 8;
        f16x8 r;
        if (e < 256) {
            const float* src = ne + (size_t)idx[a] * EMBED + e;
#pragma unroll
            for (int j = 0; j < 8; ++j) r[j] = (f16_t)src[j];
        } else {
            const float* src = team + (size_t)(a % TEAMS) * EMBED + (e - 256);
#pragma unroll
            for (int j = 0; j < 8; ++j) r[j] = (f16_t)src[j];
        }
        *(f16x8*)(vecs + (size_t)u * 8) = r;
        return;
    }
    u -= 16384;
    if (u < 16384) { // W1abT KB=16
        int c = u & 15, q = (u >> 4) & 3, kb = (u >> 6) & 15, g = u >> 10;
        *(f16x8*)(W1abT + (size_t)u * 8) = gather8(W1, kb * 32 + q * 8, g * 16 + c, HID);
        return;
    }
    u -= 16384;
    if (u < 8192) { // W1cT KB=8, base 512
        int c = u & 15, q = (u >> 4) & 3, kb = (u >> 6) & 7, g = u >> 9;
        *(f16x8*)(W1cT + (size_t)u * 8) = gather8(W1, 512 + kb * 32 + q * 8, g * 16 + c, HID);
        return;
    }
    u -= 8192;
    if (u < 8192) { // W1dT KB=8, base 768
        int c = u & 15, q = (u >> 4) & 3, kb = (u >> 6) & 7, g = u >> 9;
        *(f16x8*)(W1dT + (size_t)u * 8) = gather8(W1, 768 + kb * 32 + q * 8, g * 16 + c, HID);
        return;
    }
    u -= 8192;
    if (u < 4096) { // WsT KB=4
        int c = u & 15, q = (u >> 4) & 3, kb = (u >> 6) & 3, g = u >> 8;
        *(f16x8*)(WsT + (size_t)u * 8) = gather8(Ws, kb * 32 + q * 8, g * 16 + c, EMBED);
        return;
    }
    u -= 4096;
    if (u < 8192) { // states_h copy
        const float* src = states + (size_t)u * 8;
        f16x8 r;
#pragma unroll
        for (int j = 0; j < 8; ++j) r[j] = (f16_t)src[j];
        *(f16x8*)(states_h + (size_t)u * 8) = r;
    }
}

// ---------------- K2: prep-B + pp — pp blocks hidden under 1060 unit blocks ----------------
// blocks 0..15 : pbt rows bt0..+31 (round-13 k_pp code, coalesced reordered inputs)
// blocks 16..47: pa tile 32x64 (round-13 k_pp code)
// blocks 48..  : flat units: pf16(262144) W2s(8192) w1pt(1024)
__global__ __launch_bounds__(256, 4) void k_prepB(
    const float* __restrict__ pf, const float* __restrict__ W1,
    const float* __restrict__ W2, const f16_t* __restrict__ states_h,
    const f16_t* __restrict__ WsT, const float* __restrict__ bs,
    const f16_t* __restrict__ W1dT, const f16_t* __restrict__ vecs,
    const f16_t* __restrict__ W1abT, const f16_t* __restrict__ W1cT,
    const float* __restrict__ gpart, const float* __restrict__ b1,
    f16_t* __restrict__ W2s, f16_t* __restrict__ w1pt,
    f16_t* __restrict__ paR, f16_t* __restrict__ pbt_h,
    f16_t* __restrict__ pf16) {
    __shared__ __align__(16) f16_t se[32 * 256];
    __shared__ __align__(16) f16_t gml[256];
    const int tid = threadIdx.x;
    const int wid = tid >> 6, lane = tid & 63;
    const int c = lane & 15, q = lane >> 4;
    int bid = blockIdx.x;

    if (bid < 48) {
        if (bid >= 16) { // ---- pa path: 32x64 tile ----
            {
                float s = 0.f;
#pragma unroll 8
                for (int p = 0; p < 64; ++p) s += gpart[p * EMBED + tid];
                gml[tid] = (f16_t)(s * (1.0f / N_NODES));
            }
            __syncthreads();
            int b = bid - 16;
            const int m0 = (b >> 2) * 32, n0 = (b & 3) * 64;
            const int n = n0 + wid * 16 + c;
            const int g = n >> 4;
            f32x4 acc[2] = {f32x4{0, 0, 0, 0}, f32x4{0, 0, 0, 0}};
            for (int ks = 0; ks < 16; ++ks) {
                f16x8 bf = *(const f16x8*)(W1abT + (size_t)((g * 16 + ks) * 4 + q) * 128 + c * 8);
#pragma unroll
                for (int mi = 0; mi < 2; ++mi) {
                    f16x8 af = *(const f16x8*)(vecs + (size_t)(m0 + mi * 16 + c) * 512 + ks * 32 + q * 8);
                    acc[mi] = __builtin_amdgcn_mfma_f32_16x16x32_f16(af, bf, acc[mi], 0, 0, 0);
                }
            }
#pragma unroll
            for (int ks = 0; ks < 8; ++ks) {
                f16x8 bf = *(const f16x8*)(W1cT + (size_t)((g * 8 + ks) * 4 + q) * 128 + c * 8);
                f16x8 af = *(const f16x8*)(gml + ks * 32 + q * 8);
#pragma unroll
                for (int mi = 0; mi < 2; ++mi)
                    acc[mi] = __builtin_amdgcn_mfma_f32_16x16x32_f16(af, bf, acc[mi], 0, 0, 0);
            }
            float b1v = b1[n];
#pragma unroll
            for (int mi = 0; mi < 2; ++mi)
#pragma unroll
                for (int j = 0; j < 4; ++j) {
                    int a = m0 + mi * 16 + q * 4 + j;
                    paR[par_idx(a, n)] = (f16_t)(acc[mi][j] + b1v);
                }
            return;
        }

        // ---- pbt path: 32 rows ----
        const int bt0 = bid * 32;
        f32x4 acc[2][4];
#pragma unroll
        for (int mi = 0; mi < 2; ++mi)
#pragma unroll
            for (int ni = 0; ni < 4; ++ni) acc[mi][ni] = f32x4{0, 0, 0, 0};
#pragma unroll
        for (int ks = 0; ks < 4; ++ks) {
            f16x8 bh[4];
#pragma unroll
            for (int ni = 0; ni < 4; ++ni) {
                int g = wid * 4 + ni;
                bh[ni] = *(const f16x8*)(WsT + (size_t)((g * 4 + ks) * 4 + q) * 128 + c * 8);
            }
#pragma unroll
            for (int mi = 0; mi < 2; ++mi) {
                f16x8 af = *(const f16x8*)(states_h + (size_t)(bt0 + mi * 16 + c) * STATE + ks * 32 + q * 8);
#pragma unroll
                for (int ni = 0; ni < 4; ++ni)
                    acc[mi][ni] = __builtin_amdgcn_mfma_f32_16x16x32_f16(af, bh[ni], acc[mi][ni], 0, 0, 0);
            }
        }
#pragma unroll
        for (int mi = 0; mi < 2; ++mi)
#pragma unroll
            for (int ni = 0; ni < 4; ++ni) {
                float bsv = bs[wid * 64 + ni * 16 + c];
#pragma unroll
                for (int j = 0; j < 4; ++j) {
                    int m = mi * 16 + q * 4 + j;
                    int n = wid * 64 + ni * 16 + c;
                    se[m * 256 + (n ^ ((m & 7) << 3))] = (f16_t)fmaxf(acc[mi][ni][j] + bsv, 0.f);
                }
            }
#pragma unroll
        for (int mi = 0; mi < 2; ++mi)
#pragma unroll
            for (int ni = 0; ni < 4; ++ni) acc[mi][ni] = f32x4{0, 0, 0, 0};
        __syncthreads();
#pragma unroll
        for (int ks = 0; ks < 8; ++ks) {
            f16x8 bh[4];
#pragma unroll
            for (int ni = 0; ni < 4; ++ni) {
                int g = wid * 4 + ni;
                bh[ni] = *(const f16x8*)(W1dT + (size_t)((g * 8 + ks) * 4 + q) * 128 + c * 8);
            }
#pragma unroll
            for (int mi = 0; mi < 2; ++mi) {
                int m = mi * 16 + c;
                f16x8 ah = *(const f16x8*)(&se[m * 256 + ((ks * 32 + q * 8) ^ ((m & 7) << 3))]);
#pragma unroll
                for (int ni = 0; ni < 4; ++ni)
                    acc[mi][ni] = __builtin_amdgcn_mfma_f32_16x16x32_f16(ah, bh[ni], acc[mi][ni], 0, 0, 0);
            }
        }
#pragma unroll
        for (int mi = 0; mi < 2; ++mi)
#pragma unroll
            for (int ni = 0; ni < 4; ++ni)
#pragma unroll
                for (int j = 0; j < 4; ++j)
                    pbt_h[(size_t)(bt0 + mi * 16 + q * 4 + j) * HID + wid * 64 + ni * 16 + c] =
                        (f16_t)acc[mi][ni][j];
        return;
    }

    // ---- flat-unit segments ----
    int u = (bid - 48) * 256 + tid;
    if (u < 262144) { // pf16 [M][16]
        int m = u >> 1, h = u & 1;
        const float* row = pf + (size_t)m * PAIR_F;
        f16x8 r;
        if (h == 0) {
#pragma unroll
            for (int j = 0; j < 4; ++j) {
                float2 v = *(const float2*)(row + j * 2);
                r[j * 2] = (f16_t)v.x; r[j * 2 + 1] = (f16_t)v.y;
            }
        } else {
#pragma unroll
            for (int j = 0; j < 3; ++j) {
                float2 v = *(const float2*)(row + 8 + j * 2);
                r[j * 2] = (f16_t)v.x; r[j * 2 + 1] = (f16_t)v.y;
            }
            r[6] = (f16_t)0.f; r[7] = (f16_t)0.f;
        }
        *(f16x8*)(pf16 + (size_t)u * 8) = r;
        return;
    }
    u -= 262144;
    if (u < 8192) { // W2s KB=8
        int c2 = u & 15, q2 = (u >> 4) & 3, kb = (u >> 6) & 7, g = u >> 9;
        *(f16x8*)(W2s + (size_t)u * 8) = gather8(W2, kb * 32 + q2 * 8, g * 16 + c2, HID);
        return;
    }
    u -= 8192;
    if (u < 1024) { // w1pt KB=1, base 1024, pad 14->32
        int c2 = u & 15, q2 = (u >> 4) & 3, g = u >> 6;
        int n = g * 16 + c2, k0 = q2 * 8;
        f16x8 r;
#pragma unroll
        for (int j = 0; j < 8; ++j) {
            int k = k0 + j;
            r[j] = (f16_t)((k < PAIR_F) ? W1[(size_t)(1024 + k) * HID + n] : 0.f);
        }
        *(f16x8*)(w1pt + (size_t)u * 8) = r;
    }
}

// ---------------- K3: fused main kernel (round-13 structure, unchanged) ----------------
// BM=128: 512 thr / 8 fat waves; wave = 64 rows x 64 cols (wr=wid>>2, wc=wid&3).
__global__ __launch_bounds__(512, 4) void k_main(
    const f16_t* __restrict__ pf16, const f16_t* __restrict__ paR,
    const f16_t* __restrict__ pbt, const f16_t* __restrict__ w2s,
    const f16_t* __restrict__ w1pt, const float* __restrict__ b2,
    const float* __restrict__ W3, const float* __restrict__ b3,
    float* __restrict__ out) {
    __shared__ __align__(16) f16_t Ah[128 * 256];
    __shared__ float red[4][128];

    const int tid = threadIdx.x;
    const int wid = tid >> 6, lane = tid & 63;
    const int wr = wid >> 2, wc = wid & 3;
    const int c = lane & 15, q = lane >> 4;

    const int r0 = blockIdx.x * 128;
    const int bt = r0 >> 8;
    const int a0 = r0 & 255;

    f32x4 acc[16];
#pragma unroll
    for (int i = 0; i < 16; ++i) acc[i] = f32x4{0, 0, 0, 0};

    f16x4 pbtv[4];
#pragma unroll
    for (int nf = 0; nf < 4; ++nf)
        pbtv[nf] = *(const f16x4*)(pbt + (size_t)bt * HID + wc * 64 + nf * 16 + q * 4);

    f16x8 af[4];
#pragma unroll
    for (int nf = 0; nf < 4; ++nf) {
        int g = wc * 4 + nf;
        af[nf] = *(const f16x8*)(w1pt + (size_t)(g * 4 + q) * 128 + c * 8);
    }

    f16x4 pavA[4], pavB[4];
    {
        int n0 = wc * 64 + 0 * 16 + q * 4;
#pragma unroll
        for (int mf = 0; mf < 4; ++mf)
            pavA[mf] = *(const f16x4*)(paR + (size_t)((a0 >> 4) + wr * 4 + mf) * 4096 +
                                       (size_t)(n0 >> 2) * 64 + c * 4);
    }

    // ---- phase 1: transposed pair GEMM: D[n][m] = w1pt (A) x pf16^T (B)
#pragma unroll
    for (int mf = 0; mf < 4; ++mf) {
        int m = wr * 64 + mf * 16 + c;
        f16x8 bf;
        if (q < 2) bf = *(const f16x8*)(pf16 + (size_t)(r0 + m) * 16 + q * 8);
        else bf = f16x8{(_Float16)0, (_Float16)0, (_Float16)0, (_Float16)0,
                        (_Float16)0, (_Float16)0, (_Float16)0, (_Float16)0};
        __builtin_amdgcn_s_setprio(1);
#pragma unroll
        for (int nf = 0; nf < 4; ++nf)
            acc[nf * 4 + mf] = __builtin_amdgcn_mfma_f32_16x16x32_f16(af[nf], bf, acc[nf * 4 + mf], 0, 0, 0);
        __builtin_amdgcn_s_setprio(0);
    }

    // ---- h1 = relu(pair + pa + pbt) -> f16 (packed), swizzled LDS; pav pipelined
#pragma unroll
    for (int nf = 0; nf < 4; ++nf) {
        if (nf < 3) {
            int n1 = wc * 64 + (nf + 1) * 16 + q * 4;
#pragma unroll
            for (int mf = 0; mf < 4; ++mf)
                pavB[mf] = *(const f16x4*)(paR + (size_t)((a0 >> 4) + wr * 4 + mf) * 4096 +
                                           (size_t)(n1 >> 2) * 64 + c * 4);
        }
        int n0 = wc * 64 + nf * 16 + q * 4;
        f16x2 pb01 = {pbtv[nf][0], pbtv[nf][1]}, pb23 = {pbtv[nf][2], pbtv[nf][3]};
#pragma unroll
        for (int mf = 0; mf < 4; ++mf) {
            int m = wr * 64 + mf * 16 + c;
            f16x2 pa01 = {pavA[mf][0], pavA[mf][1]}, pa23 = {pavA[mf][2], pavA[mf][3]};
            f32x4 a = acc[nf * 4 + mf];
            f16x2 h01 = cvt_pk(a[0], a[1]);
            f16x2 h23 = cvt_pk(a[2], a[3]);
            h01 = pk_relu(h01 + pa01 + pb01);
            h23 = pk_relu(h23 + pa23 + pb23);
            f16x4 hv = __builtin_shufflevector(h01, h23, 0, 1, 2, 3);
            *(f16x4*)(&Ah[m * 256 + (n0 ^ ((m & 7) << 3))]) = hv;
        }
#pragma unroll
        for (int mf = 0; mf < 4; ++mf) pavA[mf] = pavB[mf];
    }

#pragma unroll
    for (int i = 0; i < 16; ++i) acc[i] = f32x4{0, 0, 0, 0};

    // pre-barrier B prefetch for ks=0
    f16x8 bh[4];
#pragma unroll
    for (int ni = 0; ni < 4; ++ni) {
        int g = wc * 4 + ni;
        bh[ni] = *(const f16x8*)(w2s + (size_t)((g * 8 + 0) * 4 + q) * 128 + c * 8);
    }

    __syncthreads();

    // ---- phase 2: h2 = h1[128x256] @ W2[256x256]; ah 1-deep prefetch + setprio
#pragma unroll
    for (int ks = 0; ks < 8; ++ks) {
        f16x8 bhn[4];
        if (ks < 7) {
#pragma unroll
            for (int ni = 0; ni < 4; ++ni) {
                int g = wc * 4 + ni;
                bhn[ni] = *(const f16x8*)(w2s + (size_t)((g * 8 + ks + 1) * 4 + q) * 128 + c * 8);
            }
        }
        f16x8 ahA, ahB;
        {
            int m = wr * 64 + 0 * 16 + c;
            ahA = *(const f16x8*)(&Ah[m * 256 + ((ks * 32 + q * 8) ^ ((m & 7) << 3))]);
        }
        __builtin_amdgcn_s_setprio(1);
#pragma unroll
        for (int mi = 0; mi < 4; ++mi) {
            if (mi < 3) {
                int m1 = wr * 64 + (mi + 1) * 16 + c;
                ahB = *(const f16x8*)(&Ah[m1 * 256 + ((ks * 32 + q * 8) ^ ((m1 & 7) << 3))]);
            }
#pragma unroll
            for (int ni = 0; ni < 4; ++ni)
                acc[mi * 4 + ni] = __builtin_amdgcn_mfma_f32_16x16x32_f16(ahA, bh[ni], acc[mi * 4 + ni], 0, 0, 0);
            ahA = ahB;
        }
        __builtin_amdgcn_s_setprio(0);
#pragma unroll
        for (int ni = 0; ni < 4; ++ni) bh[ni] = bhn[ni];
    }

    // ---- epilogue: score[m] = sum_n relu(h2 + b2) * W3 (+ b3)
    float p[4][4];
#pragma unroll
    for (int mi = 0; mi < 4; ++mi)
#pragma unroll
        for (int j = 0; j < 4; ++j) p[mi][j] = 0.f;
#pragma unroll
    for (int ni = 0; ni < 4; ++ni) {
        int n = wc * 64 + ni * 16 + c;
        float b2v = b2[n];
        float w3v = W3[n];
#pragma unroll
        for (int mi = 0; mi < 4; ++mi)
#pragma unroll
            for (int j = 0; j < 4; ++j)
                p[mi][j] = fmaf(fmaxf(acc[mi * 4 + ni][j] + b2v, 0.f), w3v, p[mi][j]);
    }
#pragma unroll
    for (int off = 1; off < 16; off <<= 1)
#pragma unroll
        for (int mi = 0; mi < 4; ++mi)
#pragma unroll
            for (int j = 0; j < 4; ++j) p[mi][j] += __shfl_xor(p[mi][j], off, 64);

    if (c == 0) {
#pragma unroll
        for (int mi = 0; mi < 4; ++mi)
#pragma unroll
            for (int j = 0; j < 4; ++j) red[wc][wr * 64 + mi * 16 + q * 4 + j] = p[mi][j];
    }
    __syncthreads();

    if (tid < 128) {
        out[(size_t)r0 + tid] = red[0][tid] + red[1][tid] + red[2][tid] + red[3][tid] + b3[0];
    }
}

// ---------------- launch ----------------
extern "C" void kernel_launch(void* const* d_in, const int* in_sizes, int n_in,
                              void* d_out, int out_size, void* d_ws, size_t ws_size,
                              hipStream_t stream) {
    (void)in_sizes; (void)n_in; (void)out_size; (void)ws_size;
    const float* ne     = (const float*)d_in[0];
    const float* states = (const float*)d_in[1];
    const float* pf     = (const float*)d_in[2];
    const int*   idx    = (const int*)d_in[3];
    const float* team   = (const float*)d_in[4];
    const float* Ws     = (const float*)d_in[5];
    const float* bs     = (const float*)d_in[6];
    const float* W1     = (const float*)d_in[7];
    const float* b1     = (const float*)d_in[8];
    const float* W2     = (const float*)d_in[9];
    const float* b2     = (const float*)d_in[10];
    const float* W3     = (const float*)d_in[11];
    const float* b3     = (const float*)d_in[12];
    float* out = (float*)d_out;

    char* ws = (char*)d_ws;
    float* gpart    = (float*)(ws + 0);        //  65536
    f16_t* vecs     = (f16_t*)(ws + 65536);    // 262144  [256][512]
    f16_t* W1abT    = (f16_t*)(ws + 327680);   // 262144
    f16_t* W1cT     = (f16_t*)(ws + 589824);   // 131072
    f16_t* W1dT     = (f16_t*)(ws + 720896);   // 131072
    f16_t* WsT      = (f16_t*)(ws + 851968);   //  65536
    f16_t* W2s      = (f16_t*)(ws + 917504);   // 131072
    f16_t* w1pt     = (f16_t*)(ws + 1048576);  //  16384
    f16_t* states_h = (f16_t*)(ws + 1064960);  // 131072
    f16_t* paR      = (f16_t*)(ws + 1196032);  // 131072
    f16_t* pbt_h    = (f16_t*)(ws + 1327104);  // 262144
    f16_t* pf16     = (f16_t*)(ws + 1589248);  // 4194304 (end 5783552)

    // K1: 64 colsum + (16384+16384+8192+8192+4096+8192)/256 = 240 unit blocks
    k_prepA<<<64 + 240, 256, 0, stream>>>(ne, idx, team, states, Ws, W1,
                                          gpart, vecs, W1abT, W1cT, W1dT, WsT, states_h);
    // K2: 48 pp blocks + (262144+8192+1024)/256 = 1060 unit blocks
    k_prepB<<<48 + 1060, 256, 0, stream>>>(pf, W1, W2, states_h, WsT, bs, W1dT,
                                           vecs, W1abT, W1cT, gpart, b1,
                                           W2s, w1pt, paR, pbt_h, pf16);
    k_main<<<M_TOTAL / 128, 512, 0, stream>>>(pf16, paR, pbt_h, W2s, w1pt, b2, W3, b3, out);
}